// Round 6
// baseline (137.494 us; speedup 1.0000x reference)
//
#include <hip/hip_runtime.h>
#include <hip/hip_bf16.h>
#include <cmath>

#define Bn 16
#define Nn 2048
#define Dn 1024
#define Hn 256
#define An 128

typedef __bf16 bf16x8 __attribute__((ext_vector_type(8)));
typedef float f32x4 __attribute__((ext_vector_type(4)));
typedef unsigned short ushort8v __attribute__((ext_vector_type(8)));

// barrier that does NOT drain vmcnt: global streams stay in flight across it
#define LDS_BARRIER do {                                   \
    asm volatile("s_waitcnt lgkmcnt(0)" ::: "memory");     \
    __builtin_amdgcn_s_barrier();                          \
    __builtin_amdgcn_sched_barrier(0);                     \
  } while (0)

static __device__ __forceinline__ unsigned short f2bf(float f) {
  unsigned u = __float_as_uint(f);
  u += 0x7fffu + ((u >> 16) & 1u);
  return (unsigned short)(u >> 16);
}

static __device__ __forceinline__ bf16x8 cvt8(const float4 a, const float4 b) {
  bf16x8 r;
  r[0] = (__bf16)a.x; r[1] = (__bf16)a.y; r[2] = (__bf16)a.z; r[3] = (__bf16)a.w;
  r[4] = (__bf16)b.x; r[5] = (__bf16)b.y; r[6] = (__bf16)b.z; r[7] = (__bf16)b.w;
  return r;
}

// ---------------- kernel 0: weight fp32 -> bf16 (W1 then Wa1) ----------------
__global__ __launch_bounds__(256) void conv_bf16_kernel(
    const float* __restrict__ W1, const float* __restrict__ Wa1,
    unsigned short* __restrict__ w1o, unsigned short* __restrict__ wa1o) {
  const int bid = blockIdx.x;
  const float* in;
  unsigned short* out;
  int i;
  if (bid < 128) { in = W1;  out = w1o;  i = (bid * 256 + threadIdx.x) << 3; }
  else           { in = Wa1; out = wa1o; i = ((bid - 128) * 256 + threadIdx.x) << 3; }
  const float4 a = *(const float4*)(in + i);
  const float4 b = *(const float4*)(in + i + 4);
  ushort8v u;
  u[0] = f2bf(a.x); u[1] = f2bf(a.y); u[2] = f2bf(a.z); u[3] = f2bf(a.w);
  u[4] = f2bf(b.x); u[5] = f2bf(b.y); u[6] = f2bf(b.z); u[7] = f2bf(b.w);
  *(ushort8v*)(out + i) = u;
}

// ---------------- kernel 1: fused stage1 GEMM + LN/GELU + stage2 -------------
// grid 512 x 256 thr (4 waves). Block = 64 rows, BN=256 (full H).
// K split in 4 phases of 256. A (x->bf16) reg-staged into LDS dbuf per phase;
// B (W1bf) streamed from L2 into registers, depth-1 prefetch. 4 barriers total.
__global__ __launch_bounds__(256) void fused_main(
    const float* __restrict__ x,
    const float* __restrict__ b1,
    const float* __restrict__ ln_g,
    const float* __restrict__ ln_b,
    const float* __restrict__ ba1,
    const float* __restrict__ Wa2,
    const float* __restrict__ ba2,
    const float* __restrict__ Wc,
    const float* __restrict__ bc,
    const unsigned short* __restrict__ W1bf,   // (256,1024) bf16
    const unsigned short* __restrict__ Wa1bf,  // (128,256)  bf16
    float* __restrict__ scores_out,
    float* __restrict__ logits_out)
{
  // A dbuf: 2 x [64 rows][512B] (256 k bf16, 16B-slot XOR swizzle) = 64 KB
  // epilogue: h tile 64x512B aliases buf0; red (64x8 f32) at 65536
  __shared__ __align__(16) char lds[65536 + 2048];

  const int tid  = threadIdx.x;
  const int wv   = tid >> 6;
  const int lane = tid & 63;
  const int l15  = lane & 15;
  const int lhi  = lane >> 4;
  const int rg   = wv >> 1;         // row group: rows rg*32..+32
  const int cw   = wv & 1;          // col wave:  cols cw*128..+128

  const int gr0 = blockIdx.x << 6;
  const int bb  = blockIdx.x >> 5;
  const int n0  = (blockIdx.x & 31) << 6;

  f32x4 acc[2][8];
  #pragma unroll
  for (int rf = 0; rf < 2; ++rf)
    #pragma unroll
    for (int cf = 0; cf < 8; ++cf)
      acc[rf][cf] = (f32x4){0.f, 0.f, 0.f, 0.f};

  // x staging: thread -> row sr=tid>>2, quarter sq=tid&3 (64 fp32 per phase)
  const int sr = tid >> 2, sq = tid & 3;
  const float* xbase = x + (size_t)(gr0 + sr) * Dn + (sq << 6);
  char* awbase = lds + sr * 512;

  // A-frag rows (per wave)
  const int arow0 = (rg << 5) + l15;
  const int arow1 = arow0 + 16;
  const int ax    = l15 & 7;        // (row&7), same for arow0/arow1

  // B stream base (per lane)
  const __bf16* wbL = (const __bf16*)W1bf + (size_t)((cw << 7) + l15) * Dn + (lhi << 3);

  float4 xr[16];
  bf16x8 Ba[8], Bb[8];

  #define LOADX(ph) do {                                                     \
      _Pragma("unroll") for (int j = 0; j < 16; ++j)                         \
        xr[j] = *(const float4*)(xbase + ((ph) << 8) + (j << 2));            \
    } while (0)
  #define WRITEA(pbuf) do {                                                  \
      char* ab_ = awbase + (pbuf) * 32768;                                   \
      _Pragma("unroll") for (int j = 0; j < 8; ++j) {                        \
        const bf16x8 v_ = cvt8(xr[2 * j], xr[2 * j + 1]);                    \
        *(bf16x8*)(ab_ + ((((sq << 3) + j) ^ (sr & 7)) << 4)) = v_;          \
      }                                                                      \
    } while (0)
  #define ISSUEB(arr, Kk) do {                                               \
      const __bf16* bp_ = wbL + ((Kk) << 5);                                 \
      _Pragma("unroll") for (int cf = 0; cf < 8; ++cf)                       \
        arr[cf] = *(const bf16x8*)(bp_ + (size_t)(cf << 4) * Dn);            \
    } while (0)
  #define DOMFMA(arr, Kk) do {                                               \
      const char* ab_ = lds + (((Kk) >> 3) & 1) * 32768;                     \
      const int sl_ = ((Kk) & 7) << 2;                                       \
      const bf16x8 a0_ = *(const bf16x8*)(ab_ + arow0 * 512 + (((sl_ + lhi) ^ ax) << 4)); \
      const bf16x8 a1_ = *(const bf16x8*)(ab_ + arow1 * 512 + (((sl_ + lhi) ^ ax) << 4)); \
      _Pragma("unroll") for (int cf = 0; cf < 8; ++cf) {                     \
        acc[0][cf] = __builtin_amdgcn_mfma_f32_16x16x32_bf16(a0_, arr[cf], acc[0][cf], 0, 0, 0); \
        acc[1][cf] = __builtin_amdgcn_mfma_f32_16x16x32_bf16(a1_, arr[cf], acc[1][cf], 0, 0, 0); \
      }                                                                      \
    } while (0)

  // -------- prologue: x(phase0) -> LDS buf0; B(K=0) in flight
  LOADX(0);
  ISSUEB(Ba, 0);
  WRITEA(0);
  LDS_BARRIER;

  // -------- main loop: 32 k-steps of 32; phase boundary every 8 steps
  #pragma unroll
  for (int K = 0; K < 32; ++K) {
    if (K < 31) { if (K & 1) ISSUEB(Ba, K + 1); else ISSUEB(Bb, K + 1); }
    if ((K & 7) == 0 && K < 24) LOADX((K >> 3) + 1);   // x for next phase
    if (K & 1) DOMFMA(Bb, K); else DOMFMA(Ba, K);
    if ((K & 7) == 7 && K < 31) {
      WRITEA(((K >> 3) + 1) & 1);                      // stage next phase A
      LDS_BARRIER;                                     // lgkm-only barrier
    }
  }
  __syncthreads();   // full drain; LDS reuse: h at 0 (buf0), red at 65536

  float (*red)[8] = (float(*)[8])(lds + 65536);

  // ---------------- epilogue 1: +b1, LayerNorm (cross-wave), GELU, Wc dot, pack h
  const float bc0 = bc[0];
  float b1v[8];
  #pragma unroll
  for (int cf = 0; cf < 8; ++cf) b1v[cf] = b1[(cw << 7) + (cf << 4) + l15];

  float ps[2][4], ps2[2][4];
  #pragma unroll
  for (int rf = 0; rf < 2; ++rf)
    #pragma unroll
    for (int r = 0; r < 4; ++r) { ps[rf][r] = 0.f; ps2[rf][r] = 0.f; }

  #pragma unroll
  for (int rf = 0; rf < 2; ++rf)
    #pragma unroll
    for (int cf = 0; cf < 8; ++cf)
      #pragma unroll
      for (int r = 0; r < 4; ++r) {
        const float v = acc[rf][cf][r] + b1v[cf];
        acc[rf][cf][r] = v;
        ps[rf][r] += v; ps2[rf][r] += v * v;
      }
  #pragma unroll
  for (int rf = 0; rf < 2; ++rf)
    #pragma unroll
    for (int r = 0; r < 4; ++r)
      #pragma unroll
      for (int s = 1; s < 16; s <<= 1) {
        ps[rf][r]  += __shfl_xor(ps[rf][r],  s, 64);
        ps2[rf][r] += __shfl_xor(ps2[rf][r], s, 64);
      }
  if (l15 == 0) {
    #pragma unroll
    for (int rf = 0; rf < 2; ++rf)
      #pragma unroll
      for (int r = 0; r < 4; ++r) {
        const int rowb = (rg << 5) + (rf << 4) + (lhi << 2) + r;
        red[rowb][cw << 1]       = ps[rf][r];
        red[rowb][(cw << 1) + 1] = ps2[rf][r];
      }
  }
  __syncthreads();

  float mu[2][4], inv[2][4];
  #pragma unroll
  for (int rf = 0; rf < 2; ++rf)
    #pragma unroll
    for (int r = 0; r < 4; ++r) {
      const int rowb = (rg << 5) + (rf << 4) + (lhi << 2) + r;
      const float s = red[rowb][0] + red[rowb][2];
      const float q = red[rowb][1] + red[rowb][3];
      const float m = s * (1.f / 256.f);
      const float var = q * (1.f / 256.f) - m * m;
      mu[rf][r] = m;
      inv[rf][r] = rsqrtf(var + 1e-5f);
    }

  float gv[8], bv[8], wcv[8];
  #pragma unroll
  for (int cf = 0; cf < 8; ++cf) {
    const int col = (cw << 7) + (cf << 4) + l15;
    gv[cf] = ln_g[col]; bv[cf] = ln_b[col]; wcv[cf] = Wc[col];
  }
  float sc[2][4];
  #pragma unroll
  for (int rf = 0; rf < 2; ++rf)
    #pragma unroll
    for (int r = 0; r < 4; ++r) sc[rf][r] = 0.f;

  #pragma unroll
  for (int rf = 0; rf < 2; ++rf)
    #pragma unroll
    for (int cf = 0; cf < 8; ++cf)
      #pragma unroll
      for (int r = 0; r < 4; ++r) {
        float v = (acc[rf][cf][r] - mu[rf][r]) * inv[rf][r] * gv[cf] + bv[cf];
        v = 0.5f * v * (1.f + erff(v * 0.70710678118654752f));   // exact GELU
        sc[rf][r] += v * wcv[cf];
        const int rowb = (rg << 5) + (rf << 4) + (lhi << 2) + r;
        const int col  = (cw << 7) + (cf << 4) + l15;
        *(__bf16*)(lds + rowb * 512 + (((col >> 3) ^ (rowb & 7)) << 4)
                   + ((col & 7) << 1)) = (__bf16)v;
      }
  #pragma unroll
  for (int rf = 0; rf < 2; ++rf)
    #pragma unroll
    for (int r = 0; r < 4; ++r)
      #pragma unroll
      for (int s = 1; s < 16; s <<= 1)
        sc[rf][r] += __shfl_xor(sc[rf][r], s, 64);
  if (l15 == 0) {
    #pragma unroll
    for (int rf = 0; rf < 2; ++rf)
      #pragma unroll
      for (int r = 0; r < 4; ++r) {
        const int rowb = (rg << 5) + (rf << 4) + (lhi << 2) + r;
        red[rowb][4 + cw] = sc[rf][r];
      }
  }
  __syncthreads();
  if (tid < 64)
    scores_out[(size_t)bb * Nn + n0 + tid] = red[tid][4] + red[tid][5] + bc0;

  // ---------------- stage 2: pre-act = h @ Wa1^T (per wave: 16 rows, K=256, N=128)
  f32x4 acc2[8];
  #pragma unroll
  for (int cf = 0; cf < 8; ++cf) acc2[cf] = (f32x4){0.f, 0.f, 0.f, 0.f};

  const int r16 = (wv << 4) + l15;
  #pragma unroll
  for (int ks = 0; ks < 8; ++ks) {
    const bf16x8 af = *(const bf16x8*)(lds + r16 * 512 +
                        ((((ks << 2) + lhi) ^ (r16 & 7)) << 4));
    #pragma unroll
    for (int cf = 0; cf < 8; ++cf) {
      const bf16x8 bfr = *(const bf16x8*)((const __bf16*)Wa1bf +
                          (size_t)((cf << 4) + l15) * Hn + (ks << 5) + (lhi << 3));
      acc2[cf] = __builtin_amdgcn_mfma_f32_16x16x32_bf16(af, bfr, acc2[cf], 0, 0, 0);
    }
  }
  const float ba20 = ba2[0];
  float lg[4] = {0.f, 0.f, 0.f, 0.f};
  #pragma unroll
  for (int cf = 0; cf < 8; ++cf) {
    const int col = (cf << 4) + l15;
    const float bav = ba1[col], w2v = Wa2[col];
    #pragma unroll
    for (int r = 0; r < 4; ++r) {
      const float t = acc2[cf][r] + bav;
      const float e = __expf(2.f * t);
      const float th = 1.f - 2.f / (e + 1.f);
      lg[r] += th * w2v;
    }
  }
  #pragma unroll
  for (int r = 0; r < 4; ++r)
    #pragma unroll
    for (int s = 1; s < 16; s <<= 1) lg[r] += __shfl_xor(lg[r], s, 64);
  if (l15 == 0) {
    #pragma unroll
    for (int r = 0; r < 4; ++r)
      logits_out[(size_t)bb * Nn + n0 + (wv << 4) + (lhi << 2) + r] = lg[r] + ba20;
  }
}

// ---------------- kernel 2: per-batch softmax pooling + dynamic top-k --------
__global__ __launch_bounds__(256) void finalize_kernel(
    const int* __restrict__ lengths,
    const float* __restrict__ scores,
    const float* __restrict__ logits,
    float* __restrict__ video)
{
  const int b = blockIdx.x;
  const int tid = threadIdx.x;
  __shared__ float sS[Nn];
  __shared__ float sL[Nn];
  __shared__ unsigned skey[Nn];
  __shared__ float sred[8];

  const int T = lengths[b];
  for (int i = tid; i < Nn; i += 256) {
    sS[i] = scores[(size_t)b * Nn + i];
    sL[i] = logits[(size_t)b * Nn + i];
  }
  __syncthreads();
  if (T <= 0) { if (tid == 0) video[b] = 0.f; return; }

  float m = -3.0e38f;
  for (int i = tid; i < T; i += 256) m = fmaxf(m, sL[i]);
  #pragma unroll
  for (int s = 1; s < 64; s <<= 1) m = fmaxf(m, __shfl_xor(m, s, 64));
  if ((tid & 63) == 0) sred[tid >> 6] = m;
  __syncthreads();
  m = fmaxf(fmaxf(sred[0], sred[1]), fmaxf(sred[2], sred[3]));
  __syncthreads();

  float se = 0.f, swe = 0.f;
  for (int i = tid; i < T; i += 256) {
    const float e = expf(sL[i] - m);
    se += e; swe += e * sS[i];
  }
  #pragma unroll
  for (int s = 1; s < 64; s <<= 1) { se += __shfl_xor(se, s, 64); swe += __shfl_xor(swe, s, 64); }
  if ((tid & 63) == 0) { sred[tid >> 6] = se; sred[4 + (tid >> 6)] = swe; }
  __syncthreads();
  se  = sred[0] + sred[1] + sred[2] + sred[3];
  swe = sred[4] + sred[5] + sred[6] + sred[7];
  __syncthreads();
  const float attn = swe / se;

  for (int i = tid; i < T; i += 256) {
    const unsigned u = __float_as_uint(sS[i]);
    skey[i] = (u & 0x80000000u) ? ~u : (u | 0x80000000u);
  }
  __syncthreads();
  const int k = max(1, T / 10);
  unsigned ans = 0u;
  for (int bit = 31; bit >= 0; --bit) {
    const unsigned cand = ans | (1u << bit);
    int c = 0;
    for (int i = tid; i < T; i += 256) c += (skey[i] >= cand) ? 1 : 0;
    #pragma unroll
    for (int s = 1; s < 64; s <<= 1) c += __shfl_xor(c, s, 64);
    if ((tid & 63) == 0) sred[tid >> 6] = (float)c;
    __syncthreads();
    c = (int)(sred[0] + sred[1] + sred[2] + sred[3]);
    __syncthreads();
    if (c >= k) ans = cand;
  }
  int cgt = 0; float sgt = 0.f;
  for (int i = tid; i < T; i += 256) {
    if (skey[i] > ans) { cgt++; sgt += sS[i]; }
  }
  #pragma unroll
  for (int s = 1; s < 64; s <<= 1) { cgt += __shfl_xor(cgt, s, 64); sgt += __shfl_xor(sgt, s, 64); }
  if ((tid & 63) == 0) { sred[tid >> 6] = (float)cgt; sred[4 + (tid >> 6)] = sgt; }
  __syncthreads();
  cgt = (int)(sred[0] + sred[1] + sred[2] + sred[3]);
  sgt = sred[4] + sred[5] + sred[6] + sred[7];

  const unsigned ub = (ans & 0x80000000u) ? (ans ^ 0x80000000u) : ~ans;
  const float kth = __uint_as_float(ub);
  const float topk = (sgt + (float)(k - cgt) * kth) / (float)k;
  if (tid == 0) video[b] = 0.5f * attn + 0.5f * topk;
}

extern "C" void kernel_launch(void* const* d_in, const int* in_sizes, int n_in,
                              void* d_out, int out_size, void* d_ws, size_t ws_size,
                              hipStream_t stream) {
  const float* x    = (const float*)d_in[0];
  const int*   len  = (const int*)  d_in[1];
  const float* W1   = (const float*)d_in[2];
  const float* b1   = (const float*)d_in[3];
  const float* ln_g = (const float*)d_in[4];
  const float* ln_b = (const float*)d_in[5];
  const float* Wa1  = (const float*)d_in[6];
  const float* ba1  = (const float*)d_in[7];
  const float* Wa2  = (const float*)d_in[8];
  const float* ba2  = (const float*)d_in[9];
  const float* Wc   = (const float*)d_in[10];
  const float* bc   = (const float*)d_in[11];

  float* out    = (float*)d_out;
  float* video  = out;
  float* scores = out + Bn;

  char* ws = (char*)d_ws;
  float*          logits = (float*)ws;                                   // 128KB
  unsigned short* wa1bf  = (unsigned short*)(ws + (size_t)Bn * Nn * 4);  // 64KB
  unsigned short* w1bf   = (unsigned short*)(ws + (size_t)Bn * Nn * 4 + (size_t)An * Hn * 2);

  hipLaunchKernelGGL(conv_bf16_kernel, dim3(144), dim3(256), 0, stream, W1, Wa1, w1bf, wa1bf);
  hipLaunchKernelGGL(fused_main, dim3(Bn * Nn / 64), dim3(256), 0, stream,
                     x, b1, ln_g, ln_b, ba1, Wa2, ba2, Wc, bc,
                     w1bf, wa1bf, scores, logits);
  hipLaunchKernelGGL(finalize_kernel, dim3(Bn), dim3(256), 0, stream, len, scores, logits, video);
}

// Round 7
// 89.567 us; speedup vs baseline: 1.5351x; 1.5351x over previous
//
#include <hip/hip_runtime.h>
#include <hip/hip_bf16.h>
#include <cmath>

#define Bn 16
#define Nn 2048
#define Dn 1024
#define Hn 256
#define An 128

typedef __bf16 bf16x8 __attribute__((ext_vector_type(8)));
typedef __bf16 bf16x4 __attribute__((ext_vector_type(4)));
typedef float f32x4 __attribute__((ext_vector_type(4)));
typedef unsigned short ushort8v __attribute__((ext_vector_type(8)));

// LDS layout (80 KB exactly, 2 blocks/CU):
//   A0 [0,8K)   A1 [8K,16K)    each 64 rows x 128B (64 bf16 k, 16B-slot XOR swizzle)
//   B0 [16K,48K) B1 [48K,80K)  each 256 rows x 128B
//   epilogue aliases: red (64x8 f32) at 8K (A1 dead), h tile 64x512B at 48K (B1 dead)
#define LDSA(p) ((p) * 8192)
#define LDSB(p) (16384 + (p) * 32768)
#define LDSH    49152
#define LDSRED  8192

#define PIPE_BARRIER(N) do {                                        \
    asm volatile("s_waitcnt vmcnt(" #N ") lgkmcnt(0)" ::: "memory"); \
    __builtin_amdgcn_s_barrier();                                   \
    __builtin_amdgcn_sched_barrier(0);                              \
  } while (0)

static __device__ __forceinline__ unsigned short f2bf(float f) {
  unsigned u = __float_as_uint(f);
  u += 0x7fffu + ((u >> 16) & 1u);
  return (unsigned short)(u >> 16);
}

static __device__ __forceinline__ bf16x8 cvt8(const float4 a, const float4 b) {
  bf16x8 r;
  r[0] = (__bf16)a.x; r[1] = (__bf16)a.y; r[2] = (__bf16)a.z; r[3] = (__bf16)a.w;
  r[4] = (__bf16)b.x; r[5] = (__bf16)b.y; r[6] = (__bf16)b.z; r[7] = (__bf16)b.w;
  return r;
}

static __device__ __forceinline__ void glds16(const void* g, void* l) {
  __builtin_amdgcn_global_load_lds(
      (const __attribute__((address_space(1))) unsigned int*)g,
      (__attribute__((address_space(3))) unsigned int*)l, 16, 0, 0);
}

// ---------------- kernel 0: weight fp32 -> bf16 (W1 then Wa1) ----------------
__global__ __launch_bounds__(256) void conv_bf16_kernel(
    const float* __restrict__ W1, const float* __restrict__ Wa1,
    unsigned short* __restrict__ w1o, unsigned short* __restrict__ wa1o) {
  const int bid = blockIdx.x;
  const float* in;
  unsigned short* out;
  int i;
  if (bid < 128) { in = W1;  out = w1o;  i = (bid * 256 + threadIdx.x) << 3; }
  else           { in = Wa1; out = wa1o; i = ((bid - 128) * 256 + threadIdx.x) << 3; }
  const float4 a = *(const float4*)(in + i);
  const float4 b = *(const float4*)(in + i + 4);
  ushort8v u;
  u[0] = f2bf(a.x); u[1] = f2bf(a.y); u[2] = f2bf(a.z); u[3] = f2bf(a.w);
  u[4] = f2bf(b.x); u[5] = f2bf(b.y); u[6] = f2bf(b.z); u[7] = f2bf(b.w);
  *(ushort8v*)(out + i) = u;
}

// ---------------- kernel 1: fused stage1 GEMM (pipelined) + LN/GELU + stage2 --
// grid 512 x 256 thr (4 waves). BM=64, BN=256, BK=64, 16 k-steps.
// wave tile 32 rows x 128 cols: wv = rg*2 + cw.
__global__ __launch_bounds__(256) void fused_main(
    const float* __restrict__ x,
    const float* __restrict__ b1,
    const float* __restrict__ ln_g,
    const float* __restrict__ ln_b,
    const float* __restrict__ ba1,
    const float* __restrict__ Wa2,
    const float* __restrict__ ba2,
    const float* __restrict__ Wc,
    const float* __restrict__ bc,
    const unsigned short* __restrict__ W1bf,   // (256,1024) bf16
    const unsigned short* __restrict__ Wa1bf,  // (128,256)  bf16
    float* __restrict__ scores_out,
    float* __restrict__ logits_out)
{
  __shared__ __align__(16) char lds[81920];

  const int tid  = threadIdx.x;
  const int wv   = tid >> 6;
  const int lane = tid & 63;
  const int l15  = lane & 15;
  const int lhi  = lane >> 4;
  const int rg   = wv >> 1;
  const int cw   = wv & 1;

  const int gr0 = blockIdx.x << 6;
  const int bb  = blockIdx.x >> 5;
  const int n0  = (blockIdx.x & 31) << 6;

  f32x4 acc[2][8];
  #pragma unroll
  for (int rf = 0; rf < 2; ++rf)
    #pragma unroll
    for (int cf = 0; cf < 8; ++cf)
      acc[rf][cf] = (f32x4){0.f, 0.f, 0.f, 0.f};

  // ---- x staging, COALESCED: inst j covers rows {wv*16 + j*4 + lhi} x 256B
  // contiguous (lanes l15 = consecutive 16B). 4 float4/thread/step.
  const float* xbase = x + (size_t)(gr0 + (wv << 4) + lhi) * Dn + (l15 << 2);

  // A-frag rows (per wave)
  const int arow0 = (rg << 5) + l15;
  const int arow1 = arow0 + 16;
  const int ax    = l15 & 7;        // (row&7) for A/B/h frag rows

  // B staging via glds: wave wv covers rows wv*64 + i*8 (i=0..7), 1KB per chunk.
  // source pre-swizzled so linear LDS dest yields phys slot s = logical ^ (h&7).
  const unsigned short* bsrc = W1bf + (size_t)(wv * 64 + (lane >> 3)) * Dn
                               + (((lane & 7) ^ ((lane >> 3) & 7)) << 3);

  auto issueB = [&](int p, int kc) {
    #pragma unroll
    for (int i = 0; i < 8; ++i)
      glds16(bsrc + (size_t)i * 8 * Dn + (kc << 6),
             lds + LDSB(p) + (wv * 64 + i * 8) * 128);
  };
  auto loadX = [&](float4* v, int kc) {
    #pragma unroll
    for (int j = 0; j < 4; ++j)
      v[j] = *(const float4*)(xbase + (size_t)(j << 2) * Dn + (kc << 6));
  };
  // write: row = wv*16 + j*4 + lhi; thread's float4 -> 4 bf16 (8B) at
  // slot l15>>1 (XOR row&7), half l15&1. Bank analysis: 2 accesses/bank (free).
  auto writeA = [&](int p, const float4* v) {
    #pragma unroll
    for (int j = 0; j < 4; ++j) {
      const int row = (wv << 4) + (j << 2) + lhi;
      const int xj  = ((j << 2) + lhi) & 7;
      bf16x4 t;
      t[0] = (__bf16)v[j].x; t[1] = (__bf16)v[j].y;
      t[2] = (__bf16)v[j].z; t[3] = (__bf16)v[j].w;
      *(bf16x4*)(lds + LDSA(p) + row * 128 +
                 ((((l15 >> 1) ^ xj) << 4) | ((l15 & 1) << 3))) = t;
    }
  };
  auto computeStep = [&](int p) {
    const char* Ab = lds + LDSA(p);
    const char* Bb = lds + LDSB(p);
    __builtin_amdgcn_s_setprio(1);
    #pragma unroll
    for (int ks = 0; ks < 2; ++ks) {
      const int so = (((ks << 2) + lhi) ^ ax) << 4;
      const bf16x8 aA = *(const bf16x8*)(Ab + arow0 * 128 + so);
      const bf16x8 aB = *(const bf16x8*)(Ab + arow1 * 128 + so);
      #pragma unroll
      for (int cf = 0; cf < 8; ++cf) {
        const bf16x8 bfr = *(const bf16x8*)(Bb + ((cw << 7) + (cf << 4) + l15) * 128 + so);
        acc[0][cf] = __builtin_amdgcn_mfma_f32_16x16x32_bf16(aA, bfr, acc[0][cf], 0, 0, 0);
        acc[1][cf] = __builtin_amdgcn_mfma_f32_16x16x32_bf16(aB, bfr, acc[1][cf], 0, 0, 0);
      }
    }
    __builtin_amdgcn_s_setprio(0);
  };

  // -------- prologue: B(0) glds, x(0)->A0, x(1) in regs
  // sched_barrier(0) pins VMEM issue order: glds FIRST, then x-loads — the
  // counted vmcnt below is only valid if the glds are the oldest in flight.
  float4 xr0[4], xr1[4];
  issueB(0, 0);
  __builtin_amdgcn_sched_barrier(0);
  loadX(xr0, 0);
  loadX(xr1, 1);
  __builtin_amdgcn_sched_barrier(0);
  writeA(0, xr0);           // auto-waits x(0); glds(0) drains with it
  PIPE_BARRIER(4);          // x(1) stays in flight

  // -------- main loop, fully unrolled: waits are literal constants
  #pragma unroll
  for (int kc = 0; kc < 16; ++kc) {
    const int p = kc & 1;
    const int np = p ^ 1;
    if (kc < 15) issueB(np, kc + 1);                    // 8 glds (oldest this step)
    __builtin_amdgcn_sched_barrier(0);
    if (kc < 14) loadX((kc & 1) ? xr1 : xr0, kc + 2);   // 4 x-loads (newest)
    __builtin_amdgcn_sched_barrier(0);
    computeStep(p);                                      // 20 ds_read + 32 MFMA
    if (kc < 15) {
      writeA(np, np ? xr1 : xr0);                        // x(kc+1), loaded 1 step ago
      if (kc < 14) PIPE_BARRIER(4);                      // glds done, x(kc+2) in flight
      else         PIPE_BARRIER(0);                      // tail: drain all
    }
  }
  __syncthreads();   // LDS repurpose: h at LDSH (B1), red at LDSRED (A1)

  float (*red)[8] = (float(*)[8])(lds + LDSRED);

  // ---------------- epilogue 1: +b1, LayerNorm (cross-wave), GELU, Wc dot, pack h
  const float bc0 = bc[0];
  float b1v[8];
  #pragma unroll
  for (int cf = 0; cf < 8; ++cf) b1v[cf] = b1[(cw << 7) + (cf << 4) + l15];

  float ps[2][4], ps2[2][4];
  #pragma unroll
  for (int rf = 0; rf < 2; ++rf)
    #pragma unroll
    for (int r = 0; r < 4; ++r) { ps[rf][r] = 0.f; ps2[rf][r] = 0.f; }

  #pragma unroll
  for (int rf = 0; rf < 2; ++rf)
    #pragma unroll
    for (int cf = 0; cf < 8; ++cf)
      #pragma unroll
      for (int r = 0; r < 4; ++r) {
        const float v = acc[rf][cf][r] + b1v[cf];
        acc[rf][cf][r] = v;
        ps[rf][r] += v; ps2[rf][r] += v * v;
      }
  #pragma unroll
  for (int rf = 0; rf < 2; ++rf)
    #pragma unroll
    for (int r = 0; r < 4; ++r)
      #pragma unroll
      for (int s = 1; s < 16; s <<= 1) {
        ps[rf][r]  += __shfl_xor(ps[rf][r],  s, 64);
        ps2[rf][r] += __shfl_xor(ps2[rf][r], s, 64);
      }
  if (l15 == 0) {
    #pragma unroll
    for (int rf = 0; rf < 2; ++rf)
      #pragma unroll
      for (int r = 0; r < 4; ++r) {
        const int rowb = (rg << 5) + (rf << 4) + (lhi << 2) + r;
        red[rowb][cw << 1]       = ps[rf][r];
        red[rowb][(cw << 1) + 1] = ps2[rf][r];
      }
  }
  __syncthreads();

  float mu[2][4], inv[2][4];
  #pragma unroll
  for (int rf = 0; rf < 2; ++rf)
    #pragma unroll
    for (int r = 0; r < 4; ++r) {
      const int rowb = (rg << 5) + (rf << 4) + (lhi << 2) + r;
      const float s = red[rowb][0] + red[rowb][2];
      const float q = red[rowb][1] + red[rowb][3];
      const float m = s * (1.f / 256.f);
      const float var = q * (1.f / 256.f) - m * m;
      mu[rf][r] = m;
      inv[rf][r] = rsqrtf(var + 1e-5f);
    }

  float gv[8], bv[8], wcv[8];
  #pragma unroll
  for (int cf = 0; cf < 8; ++cf) {
    const int col = (cw << 7) + (cf << 4) + l15;
    gv[cf] = ln_g[col]; bv[cf] = ln_b[col]; wcv[cf] = Wc[col];
  }
  float sc[2][4];
  #pragma unroll
  for (int rf = 0; rf < 2; ++rf)
    #pragma unroll
    for (int r = 0; r < 4; ++r) sc[rf][r] = 0.f;

  #pragma unroll
  for (int rf = 0; rf < 2; ++rf)
    #pragma unroll
    for (int cf = 0; cf < 8; ++cf)
      #pragma unroll
      for (int r = 0; r < 4; ++r) {
        float v = (acc[rf][cf][r] - mu[rf][r]) * inv[rf][r] * gv[cf] + bv[cf];
        v = 0.5f * v * (1.f + erff(v * 0.70710678118654752f));   // exact GELU
        sc[rf][r] += v * wcv[cf];
        const int rowb = (rg << 5) + (rf << 4) + (lhi << 2) + r;
        const int col  = (cw << 7) + (cf << 4) + l15;
        *(__bf16*)(lds + LDSH + rowb * 512 + (((col >> 3) ^ (rowb & 7)) << 4)
                   + ((col & 7) << 1)) = (__bf16)v;
      }
  #pragma unroll
  for (int rf = 0; rf < 2; ++rf)
    #pragma unroll
    for (int r = 0; r < 4; ++r)
      #pragma unroll
      for (int s = 1; s < 16; s <<= 1)
        sc[rf][r] += __shfl_xor(sc[rf][r], s, 64);
  if (l15 == 0) {
    #pragma unroll
    for (int rf = 0; rf < 2; ++rf)
      #pragma unroll
      for (int r = 0; r < 4; ++r) {
        const int rowb = (rg << 5) + (rf << 4) + (lhi << 2) + r;
        red[rowb][4 + cw] = sc[rf][r];
      }
  }
  __syncthreads();
  if (tid < 64)
    scores_out[(size_t)bb * Nn + n0 + tid] = red[tid][4] + red[tid][5] + bc0;

  // ---------------- stage 2: pre-act = h @ Wa1^T (per wave: 16 rows, K=256, N=128)
  f32x4 acc2[8];
  #pragma unroll
  for (int cf = 0; cf < 8; ++cf) acc2[cf] = (f32x4){0.f, 0.f, 0.f, 0.f};

  const int r16 = (wv << 4) + l15;
  #pragma unroll
  for (int ks = 0; ks < 8; ++ks) {
    const bf16x8 af = *(const bf16x8*)(lds + LDSH + r16 * 512 +
                        ((((ks << 2) + lhi) ^ (r16 & 7)) << 4));
    #pragma unroll
    for (int cf = 0; cf < 8; ++cf) {
      const bf16x8 bfr = *(const bf16x8*)((const __bf16*)Wa1bf +
                          (size_t)((cf << 4) + l15) * Hn + (ks << 5) + (lhi << 3));
      acc2[cf] = __builtin_amdgcn_mfma_f32_16x16x32_bf16(af, bfr, acc2[cf], 0, 0, 0);
    }
  }
  const float ba20 = ba2[0];
  float lg[4] = {0.f, 0.f, 0.f, 0.f};
  #pragma unroll
  for (int cf = 0; cf < 8; ++cf) {
    const int col = (cf << 4) + l15;
    const float bav = ba1[col], w2v = Wa2[col];
    #pragma unroll
    for (int r = 0; r < 4; ++r) {
      const float t = acc2[cf][r] + bav;
      const float e = __expf(2.f * t);
      const float th = 1.f - 2.f / (e + 1.f);
      lg[r] += th * w2v;
    }
  }
  #pragma unroll
  for (int r = 0; r < 4; ++r)
    #pragma unroll
    for (int s = 1; s < 16; s <<= 1) lg[r] += __shfl_xor(lg[r], s, 64);
  if (l15 == 0) {
    #pragma unroll
    for (int r = 0; r < 4; ++r)
      logits_out[(size_t)bb * Nn + n0 + (wv << 4) + (lhi << 2) + r] = lg[r] + ba20;
  }
}

// ---------------- kernel 2: per-batch softmax pooling + dynamic top-k --------
__global__ __launch_bounds__(256) void finalize_kernel(
    const int* __restrict__ lengths,
    const float* __restrict__ scores,
    const float* __restrict__ logits,
    float* __restrict__ video)
{
  const int b = blockIdx.x;
  const int tid = threadIdx.x;
  __shared__ float sS[Nn];
  __shared__ float sL[Nn];
  __shared__ unsigned skey[Nn];
  __shared__ float sred[8];

  const int T = lengths[b];
  for (int i = tid; i < Nn; i += 256) {
    sS[i] = scores[(size_t)b * Nn + i];
    sL[i] = logits[(size_t)b * Nn + i];
  }
  __syncthreads();
  if (T <= 0) { if (tid == 0) video[b] = 0.f; return; }

  float m = -3.0e38f;
  for (int i = tid; i < T; i += 256) m = fmaxf(m, sL[i]);
  #pragma unroll
  for (int s = 1; s < 64; s <<= 1) m = fmaxf(m, __shfl_xor(m, s, 64));
  if ((tid & 63) == 0) sred[tid >> 6] = m;
  __syncthreads();
  m = fmaxf(fmaxf(sred[0], sred[1]), fmaxf(sred[2], sred[3]));
  __syncthreads();

  float se = 0.f, swe = 0.f;
  for (int i = tid; i < T; i += 256) {
    const float e = expf(sL[i] - m);
    se += e; swe += e * sS[i];
  }
  #pragma unroll
  for (int s = 1; s < 64; s <<= 1) { se += __shfl_xor(se, s, 64); swe += __shfl_xor(swe, s, 64); }
  if ((tid & 63) == 0) { sred[tid >> 6] = se; sred[4 + (tid >> 6)] = swe; }
  __syncthreads();
  se  = sred[0] + sred[1] + sred[2] + sred[3];
  swe = sred[4] + sred[5] + sred[6] + sred[7];
  __syncthreads();
  const float attn = swe / se;

  for (int i = tid; i < T; i += 256) {
    const unsigned u = __float_as_uint(sS[i]);
    skey[i] = (u & 0x80000000u) ? ~u : (u | 0x80000000u);
  }
  __syncthreads();
  const int k = max(1, T / 10);
  unsigned ans = 0u;
  for (int bit = 31; bit >= 0; --bit) {
    const unsigned cand = ans | (1u << bit);
    int c = 0;
    for (int i = tid; i < T; i += 256) c += (skey[i] >= cand) ? 1 : 0;
    #pragma unroll
    for (int s = 1; s < 64; s <<= 1) c += __shfl_xor(c, s, 64);
    if ((tid & 63) == 0) sred[tid >> 6] = (float)c;
    __syncthreads();
    c = (int)(sred[0] + sred[1] + sred[2] + sred[3]);
    __syncthreads();
    if (c >= k) ans = cand;
  }
  int cgt = 0; float sgt = 0.f;
  for (int i = tid; i < T; i += 256) {
    if (skey[i] > ans) { cgt++; sgt += sS[i]; }
  }
  #pragma unroll
  for (int s = 1; s < 64; s <<= 1) { cgt += __shfl_xor(cgt, s, 64); sgt += __shfl_xor(sgt, s, 64); }
  if ((tid & 63) == 0) { sred[tid >> 6] = (float)cgt; sred[4 + (tid >> 6)] = sgt; }
  __syncthreads();
  cgt = (int)(sred[0] + sred[1] + sred[2] + sred[3]);
  sgt = sred[4] + sred[5] + sred[6] + sred[7];

  const unsigned ub = (ans & 0x80000000u) ? (ans ^ 0x80000000u) : ~ans;
  const float kth = __uint_as_float(ub);
  const float topk = (sgt + (float)(k - cgt) * kth) / (float)k;
  if (tid == 0) video[b] = 0.5f * attn + 0.5f * topk;
}

extern "C" void kernel_launch(void* const* d_in, const int* in_sizes, int n_in,
                              void* d_out, int out_size, void* d_ws, size_t ws_size,
                              hipStream_t stream) {
  const float* x    = (const float*)d_in[0];
  const int*   len  = (const int*)  d_in[1];
  const float* W1   = (const float*)d_in[2];
  const float* b1   = (const float*)d_in[3];
  const float* ln_g = (const float*)d_in[4];
  const float* ln_b = (const float*)d_in[5];
  const float* Wa1  = (const float*)d_in[6];
  const float* ba1  = (const float*)d_in[7];
  const float* Wa2  = (const float*)d_in[8];
  const float* ba2  = (const float*)d_in[9];
  const float* Wc   = (const float*)d_in[10];
  const float* bc   = (const float*)d_in[11];

  float* out    = (float*)d_out;
  float* video  = out;
  float* scores = out + Bn;

  char* ws = (char*)d_ws;
  float*          logits = (float*)ws;                                   // 128KB
  unsigned short* wa1bf  = (unsigned short*)(ws + (size_t)Bn * Nn * 4);  // 64KB
  unsigned short* w1bf   = (unsigned short*)(ws + (size_t)Bn * Nn * 4 + (size_t)An * Hn * 2);

  hipLaunchKernelGGL(conv_bf16_kernel, dim3(144), dim3(256), 0, stream, W1, Wa1, w1bf, wa1bf);
  hipLaunchKernelGGL(fused_main, dim3(Bn * Nn / 64), dim3(256), 0, stream,
                     x, b1, ln_g, ln_b, ba1, Wa2, ba2, Wc, bc,
                     w1bf, wa1bf, scores, logits);
  hipLaunchKernelGGL(finalize_kernel, dim3(Bn), dim3(256), 0, stream, len, scores, logits, video);
}

// Round 8
// 83.563 us; speedup vs baseline: 1.6454x; 1.0719x over previous
//
#include <hip/hip_runtime.h>
#include <hip/hip_bf16.h>
#include <cmath>

#define Bn 16
#define Nn 2048
#define Dn 1024
#define Hn 256
#define An 128

typedef __bf16 bf16x8 __attribute__((ext_vector_type(8)));
typedef __bf16 bf16x4 __attribute__((ext_vector_type(4)));
typedef float f32x4 __attribute__((ext_vector_type(4)));
typedef unsigned short ushort8v __attribute__((ext_vector_type(8)));

// LDS layout, 132 KB, 1 block/CU (8 waves):
//   A dbuf   [0,32K)    2 x 128 rows x 128B   (main loop)
//   B dbuf   [32K,96K)  2 x 256 rows x 128B   (main loop)
//   Wa1 p0   [96K,128K) rows 0..63  x 512B    (whole kernel)
//   Wa1 p1   [0,32K)    rows 64..127 x 512B   (after main loop; A dead)
//   h        [32K,96K)  128 rows x 512B       (after main loop; B dead)
//   red      [128K,132K) 128 x 8 f32
#define LDSA(p) ((p) * 16384)
#define LDSB(p) (32768 + (p) * 32768)
#define LDSH    32768
#define LDSW0   98304
#define LDSRED  131072

#define PIPE_BARRIER(N) do {                                        \
    asm volatile("s_waitcnt vmcnt(" #N ") lgkmcnt(0)" ::: "memory"); \
    __builtin_amdgcn_s_barrier();                                   \
    __builtin_amdgcn_sched_barrier(0);                              \
  } while (0)

static __device__ __forceinline__ unsigned short f2bf(float f) {
  unsigned u = __float_as_uint(f);
  u += 0x7fffu + ((u >> 16) & 1u);
  return (unsigned short)(u >> 16);
}

static __device__ __forceinline__ bf16x8 cvt8(const float4 a, const float4 b) {
  bf16x8 r;
  r[0] = (__bf16)a.x; r[1] = (__bf16)a.y; r[2] = (__bf16)a.z; r[3] = (__bf16)a.w;
  r[4] = (__bf16)b.x; r[5] = (__bf16)b.y; r[6] = (__bf16)b.z; r[7] = (__bf16)b.w;
  return r;
}

static __device__ __forceinline__ void glds16(const void* g, void* l) {
  __builtin_amdgcn_global_load_lds(
      (const __attribute__((address_space(1))) unsigned int*)g,
      (__attribute__((address_space(3))) unsigned int*)l, 16, 0, 0);
}

// ---------------- kernel 0: weight fp32 -> bf16 (W1 then Wa1) ----------------
__global__ __launch_bounds__(256) void conv_bf16_kernel(
    const float* __restrict__ W1, const float* __restrict__ Wa1,
    unsigned short* __restrict__ w1o, unsigned short* __restrict__ wa1o) {
  const int bid = blockIdx.x;
  const float* in;
  unsigned short* out;
  int i;
  if (bid < 128) { in = W1;  out = w1o;  i = (bid * 256 + threadIdx.x) << 3; }
  else           { in = Wa1; out = wa1o; i = ((bid - 128) * 256 + threadIdx.x) << 3; }
  const float4 a = *(const float4*)(in + i);
  const float4 b = *(const float4*)(in + i + 4);
  ushort8v u;
  u[0] = f2bf(a.x); u[1] = f2bf(a.y); u[2] = f2bf(a.z); u[3] = f2bf(a.w);
  u[4] = f2bf(b.x); u[5] = f2bf(b.y); u[6] = f2bf(b.z); u[7] = f2bf(b.w);
  *(ushort8v*)(out + i) = u;
}

// ---------------- kernel 1: fused stage1 GEMM (pipelined) + LN/GELU + stage2 --
// grid 256 x 512 thr (8 waves, 1 block/CU). BM=128, BN=256, BK=64, 16 k-steps.
// wave tile 32 rows x 128 cols: wv = rg*2 + cw  (rg 0..3, cw 0..1).
__global__ __launch_bounds__(512) void fused_main(
    const float* __restrict__ x,
    const float* __restrict__ b1,
    const float* __restrict__ ln_g,
    const float* __restrict__ ln_b,
    const float* __restrict__ ba1,
    const float* __restrict__ Wa2,
    const float* __restrict__ ba2,
    const float* __restrict__ Wc,
    const float* __restrict__ bc,
    const unsigned short* __restrict__ W1bf,   // (256,1024) bf16
    const unsigned short* __restrict__ Wa1bf,  // (128,256)  bf16
    float* __restrict__ scores_out,
    float* __restrict__ logits_out)
{
  __shared__ __align__(16) char lds[135168];

  const int tid  = threadIdx.x;
  const int wv   = tid >> 6;        // 0..7
  const int lane = tid & 63;
  const int l15  = lane & 15;
  const int lhi  = lane >> 4;
  const int rg   = wv >> 1;         // rows rg*32..+32
  const int cw   = wv & 1;          // cols cw*128..+128

  const int gr0 = blockIdx.x << 7;  // 128 rows per block
  const int bb  = gr0 >> 11;
  const int n0  = gr0 & (Nn - 1);

  f32x4 acc[2][8];
  #pragma unroll
  for (int rf = 0; rf < 2; ++rf)
    #pragma unroll
    for (int cf = 0; cf < 8; ++cf)
      acc[rf][cf] = (f32x4){0.f, 0.f, 0.f, 0.f};

  // x staging (coalesced): instr j covers rows wv*16 + j*4 + lhi, 256B contiguous
  const float* xbase = x + (size_t)(gr0 + (wv << 4) + lhi) * Dn + (l15 << 2);

  // A-frag rows
  const int arow0 = (rg << 5) + l15;
  const int arow1 = arow0 + 16;
  const int ax    = l15 & 7;

  // B staging via glds: wave wv covers rows wv*32 + i*8 (i=0..3), 1KB/chunk.
  // source pre-swizzled: phys slot s holds logical s ^ (row&7).
  const unsigned short* bsrc = W1bf + (size_t)(wv * 32 + (lane >> 3)) * Dn
                               + (((lane & 7) ^ ((lane >> 3) & 7)) << 3);

  // Wa1 staging: per wave 8 rows per part; glds i covers 2 rows (lane>>5).
  const int warow = (lane >> 5);              // 0..1
  const int waslot = lane & 31;               // 16B slot in 512B row

  auto issueB = [&](int p, int kc) {
    #pragma unroll
    for (int i = 0; i < 4; ++i)
      glds16(bsrc + (size_t)i * 8 * Dn + (kc << 6),
             lds + LDSB(p) + (wv * 32 + i * 8) * 128);
  };
  auto issueWa1 = [&](int part, int ldsbase) {
    #pragma unroll
    for (int i = 0; i < 4; ++i) {
      const int lrow = wv * 8 + i * 2 + warow;          // 0..63 within part
      const int grow = part * 64 + lrow;
      glds16((const __bf16*)Wa1bf + (size_t)grow * Hn + ((waslot ^ (lrow & 7)) << 3),
             lds + ldsbase + (wv * 8 + i * 2) * 512);
    }
  };
  auto loadX = [&](float4* v, int kc) {
    #pragma unroll
    for (int j = 0; j < 4; ++j)
      v[j] = *(const float4*)(xbase + (size_t)(j << 2) * Dn + (kc << 6));
  };
  auto writeA = [&](int p, const float4* v) {
    #pragma unroll
    for (int j = 0; j < 4; ++j) {
      const int row = (wv << 4) + (j << 2) + lhi;
      const int xj  = ((j << 2) + lhi) & 7;             // row&7
      bf16x4 t;
      t[0] = (__bf16)v[j].x; t[1] = (__bf16)v[j].y;
      t[2] = (__bf16)v[j].z; t[3] = (__bf16)v[j].w;
      *(bf16x4*)(lds + LDSA(p) + row * 128 +
                 ((((l15 >> 1) ^ xj) << 4) | ((l15 & 1) << 3))) = t;
    }
  };
  auto computeStep = [&](int p) {
    const char* Ab = lds + LDSA(p);
    const char* Bb = lds + LDSB(p);
    __builtin_amdgcn_s_setprio(1);
    #pragma unroll
    for (int ks = 0; ks < 2; ++ks) {
      const int so = (((ks << 2) + lhi) ^ ax) << 4;
      const bf16x8 aA = *(const bf16x8*)(Ab + arow0 * 128 + so);
      const bf16x8 aB = *(const bf16x8*)(Ab + arow1 * 128 + so);
      #pragma unroll
      for (int cf = 0; cf < 8; ++cf) {
        const bf16x8 bfr = *(const bf16x8*)(Bb + ((cw << 7) + (cf << 4) + l15) * 128 + so);
        acc[0][cf] = __builtin_amdgcn_mfma_f32_16x16x32_bf16(aA, bfr, acc[0][cf], 0, 0, 0);
        acc[1][cf] = __builtin_amdgcn_mfma_f32_16x16x32_bf16(aB, bfr, acc[1][cf], 0, 0, 0);
      }
    }
    __builtin_amdgcn_s_setprio(0);
  };

  // -------- prologue: Wa1 part0 + B(0) glds (oldest), x(0), x(1)
  float4 xr0[4], xr1[4];
  issueWa1(0, LDSW0);
  issueB(0, 0);
  __builtin_amdgcn_sched_barrier(0);
  loadX(xr0, 0);
  loadX(xr1, 1);
  __builtin_amdgcn_sched_barrier(0);
  writeA(0, xr0);           // auto-waits x(0); Wa1+B(0) drain with it
  PIPE_BARRIER(4);          // x(1) stays in flight

  // -------- main loop, fully unrolled
  #pragma unroll
  for (int kc = 0; kc < 16; ++kc) {
    const int p = kc & 1;
    const int np = p ^ 1;
    if (kc < 15) issueB(np, kc + 1);                    // 4 glds (oldest this step)
    __builtin_amdgcn_sched_barrier(0);
    if (kc < 14) loadX((kc & 1) ? xr1 : xr0, kc + 2);   // 4 x-loads (newest)
    __builtin_amdgcn_sched_barrier(0);
    computeStep(p);
    if (kc < 15) {
      writeA(np, np ? xr1 : xr0);
      if (kc < 14) PIPE_BARRIER(4);
      else         PIPE_BARRIER(0);
    }
  }
  __syncthreads();   // LDS repurpose: h at LDSH (B), Wa1 p1 into A region

  issueWa1(1, 0);    // Wa1 rows 64..127 -> [0,32K); drains at next __syncthreads

  float (*red)[8] = (float(*)[8])(lds + LDSRED);

  // ---------------- epilogue 1: +b1, LayerNorm (cross-wave), GELU, Wc dot, pack h
  const float bc0 = bc[0];
  float b1v[8];
  #pragma unroll
  for (int cf = 0; cf < 8; ++cf) b1v[cf] = b1[(cw << 7) + (cf << 4) + l15];

  float ps[2][4], ps2[2][4];
  #pragma unroll
  for (int rf = 0; rf < 2; ++rf)
    #pragma unroll
    for (int r = 0; r < 4; ++r) { ps[rf][r] = 0.f; ps2[rf][r] = 0.f; }

  #pragma unroll
  for (int rf = 0; rf < 2; ++rf)
    #pragma unroll
    for (int cf = 0; cf < 8; ++cf)
      #pragma unroll
      for (int r = 0; r < 4; ++r) {
        const float v = acc[rf][cf][r] + b1v[cf];
        acc[rf][cf][r] = v;
        ps[rf][r] += v; ps2[rf][r] += v * v;
      }
  #pragma unroll
  for (int rf = 0; rf < 2; ++rf)
    #pragma unroll
    for (int r = 0; r < 4; ++r)
      #pragma unroll
      for (int s = 1; s < 16; s <<= 1) {
        ps[rf][r]  += __shfl_xor(ps[rf][r],  s, 64);
        ps2[rf][r] += __shfl_xor(ps2[rf][r], s, 64);
      }
  if (l15 == 0) {
    #pragma unroll
    for (int rf = 0; rf < 2; ++rf)
      #pragma unroll
      for (int r = 0; r < 4; ++r) {
        const int rowb = (rg << 5) + (rf << 4) + (lhi << 2) + r;
        red[rowb][cw << 1]       = ps[rf][r];
        red[rowb][(cw << 1) + 1] = ps2[rf][r];
      }
  }
  __syncthreads();   // also drains Wa1 part1 glds

  float mu[2][4], inv[2][4];
  #pragma unroll
  for (int rf = 0; rf < 2; ++rf)
    #pragma unroll
    for (int r = 0; r < 4; ++r) {
      const int rowb = (rg << 5) + (rf << 4) + (lhi << 2) + r;
      const float s = red[rowb][0] + red[rowb][2];
      const float q = red[rowb][1] + red[rowb][3];
      const float m = s * (1.f / 256.f);
      const float var = q * (1.f / 256.f) - m * m;
      mu[rf][r] = m;
      inv[rf][r] = rsqrtf(var + 1e-5f);
    }

  float gv[8], bv[8], wcv[8];
  #pragma unroll
  for (int cf = 0; cf < 8; ++cf) {
    const int col = (cw << 7) + (cf << 4) + l15;
    gv[cf] = ln_g[col]; bv[cf] = ln_b[col]; wcv[cf] = Wc[col];
  }
  float sc[2][4];
  #pragma unroll
  for (int rf = 0; rf < 2; ++rf)
    #pragma unroll
    for (int r = 0; r < 4; ++r) sc[rf][r] = 0.f;

  #pragma unroll
  for (int rf = 0; rf < 2; ++rf)
    #pragma unroll
    for (int cf = 0; cf < 8; ++cf)
      #pragma unroll
      for (int r = 0; r < 4; ++r) {
        float v = (acc[rf][cf][r] - mu[rf][r]) * inv[rf][r] * gv[cf] + bv[cf];
        v = 0.5f * v * (1.f + erff(v * 0.70710678118654752f));   // exact GELU
        sc[rf][r] += v * wcv[cf];
        const int rowb = (rg << 5) + (rf << 4) + (lhi << 2) + r;
        const int col  = (cw << 7) + (cf << 4) + l15;
        *(__bf16*)(lds + LDSH + rowb * 512 + (((col >> 3) ^ (rowb & 7)) << 4)
                   + ((col & 7) << 1)) = (__bf16)v;
      }
  #pragma unroll
  for (int rf = 0; rf < 2; ++rf)
    #pragma unroll
    for (int r = 0; r < 4; ++r)
      #pragma unroll
      for (int s = 1; s < 16; s <<= 1)
        sc[rf][r] += __shfl_xor(sc[rf][r], s, 64);
  if (l15 == 0) {
    #pragma unroll
    for (int rf = 0; rf < 2; ++rf)
      #pragma unroll
      for (int r = 0; r < 4; ++r) {
        const int rowb = (rg << 5) + (rf << 4) + (lhi << 2) + r;
        red[rowb][4 + cw] = sc[rf][r];
      }
  }
  __syncthreads();
  if (tid < 128)
    scores_out[(size_t)bb * Nn + n0 + tid] = red[tid][4] + red[tid][5] + bc0;

  // ---------------- stage 2: pre-act = h @ Wa1^T (per wave: 16 rows, K=256, N=128)
  // h from LDS (swizzled); Wa1 from LDS (part0 at LDSW0, part1 at 0)
  f32x4 acc2[8];
  #pragma unroll
  for (int cf = 0; cf < 8; ++cf) acc2[cf] = (f32x4){0.f, 0.f, 0.f, 0.f};

  const int r16 = (wv << 4) + l15;
  #pragma unroll
  for (int ks = 0; ks < 8; ++ks) {
    const bf16x8 af = *(const bf16x8*)(lds + LDSH + r16 * 512 +
                        ((((ks << 2) + lhi) ^ (r16 & 7)) << 4));
    #pragma unroll
    for (int cf = 0; cf < 8; ++cf) {
      const int rr = (cf << 4) + l15;                 // Wa1 row 0..127
      const char* wbase = (cf < 4) ? lds + LDSW0 + rr * 512
                                   : lds + (rr & 63) * 512;
      const bf16x8 bfr = *(const bf16x8*)(wbase + ((((ks << 2) + lhi) ^ ax) << 4));
      acc2[cf] = __builtin_amdgcn_mfma_f32_16x16x32_bf16(af, bfr, acc2[cf], 0, 0, 0);
    }
  }
  const float ba20 = ba2[0];
  float lg[4] = {0.f, 0.f, 0.f, 0.f};
  #pragma unroll
  for (int cf = 0; cf < 8; ++cf) {
    const int col = (cf << 4) + l15;
    const float bav = ba1[col], w2v = Wa2[col];
    #pragma unroll
    for (int r = 0; r < 4; ++r) {
      const float t = acc2[cf][r] + bav;
      const float e = __expf(2.f * t);
      const float th = 1.f - 2.f / (e + 1.f);
      lg[r] += th * w2v;
    }
  }
  #pragma unroll
  for (int r = 0; r < 4; ++r)
    #pragma unroll
    for (int s = 1; s < 16; s <<= 1) lg[r] += __shfl_xor(lg[r], s, 64);
  if (l15 == 0) {
    #pragma unroll
    for (int r = 0; r < 4; ++r)
      logits_out[(size_t)bb * Nn + n0 + (wv << 4) + (lhi << 2) + r] = lg[r] + ba20;
  }
}

// ---------------- kernel 2: per-batch softmax pooling + dynamic top-k --------
__global__ __launch_bounds__(256) void finalize_kernel(
    const int* __restrict__ lengths,
    const float* __restrict__ scores,
    const float* __restrict__ logits,
    float* __restrict__ video)
{
  const int b = blockIdx.x;
  const int tid = threadIdx.x;
  __shared__ float sS[Nn];
  __shared__ float sL[Nn];
  __shared__ unsigned skey[Nn];
  __shared__ float sred[8];

  const int T = lengths[b];
  for (int i = tid; i < Nn; i += 256) {
    sS[i] = scores[(size_t)b * Nn + i];
    sL[i] = logits[(size_t)b * Nn + i];
  }
  __syncthreads();
  if (T <= 0) { if (tid == 0) video[b] = 0.f; return; }

  float m = -3.0e38f;
  for (int i = tid; i < T; i += 256) m = fmaxf(m, sL[i]);
  #pragma unroll
  for (int s = 1; s < 64; s <<= 1) m = fmaxf(m, __shfl_xor(m, s, 64));
  if ((tid & 63) == 0) sred[tid >> 6] = m;
  __syncthreads();
  m = fmaxf(fmaxf(sred[0], sred[1]), fmaxf(sred[2], sred[3]));
  __syncthreads();

  float se = 0.f, swe = 0.f;
  for (int i = tid; i < T; i += 256) {
    const float e = expf(sL[i] - m);
    se += e; swe += e * sS[i];
  }
  #pragma unroll
  for (int s = 1; s < 64; s <<= 1) { se += __shfl_xor(se, s, 64); swe += __shfl_xor(swe, s, 64); }
  if ((tid & 63) == 0) { sred[tid >> 6] = se; sred[4 + (tid >> 6)] = swe; }
  __syncthreads();
  se  = sred[0] + sred[1] + sred[2] + sred[3];
  swe = sred[4] + sred[5] + sred[6] + sred[7];
  __syncthreads();
  const float attn = swe / se;

  for (int i = tid; i < T; i += 256) {
    const unsigned u = __float_as_uint(sS[i]);
    skey[i] = (u & 0x80000000u) ? ~u : (u | 0x80000000u);
  }
  __syncthreads();
  const int k = max(1, T / 10);
  unsigned ans = 0u;
  for (int bit = 31; bit >= 0; --bit) {
    const unsigned cand = ans | (1u << bit);
    int c = 0;
    for (int i = tid; i < T; i += 256) c += (skey[i] >= cand) ? 1 : 0;
    #pragma unroll
    for (int s = 1; s < 64; s <<= 1) c += __shfl_xor(c, s, 64);
    if ((tid & 63) == 0) sred[tid >> 6] = (float)c;
    __syncthreads();
    c = (int)(sred[0] + sred[1] + sred[2] + sred[3]);
    __syncthreads();
    if (c >= k) ans = cand;
  }
  int cgt = 0; float sgt = 0.f;
  for (int i = tid; i < T; i += 256) {
    if (skey[i] > ans) { cgt++; sgt += sS[i]; }
  }
  #pragma unroll
  for (int s = 1; s < 64; s <<= 1) { cgt += __shfl_xor(cgt, s, 64); sgt += __shfl_xor(sgt, s, 64); }
  if ((tid & 63) == 0) { sred[tid >> 6] = (float)cgt; sred[4 + (tid >> 6)] = sgt; }
  __syncthreads();
  cgt = (int)(sred[0] + sred[1] + sred[2] + sred[3]);
  sgt = sred[4] + sred[5] + sred[6] + sred[7];

  const unsigned ub = (ans & 0x80000000u) ? (ans ^ 0x80000000u) : ~ans;
  const float kth = __uint_as_float(ub);
  const float topk = (sgt + (float)(k - cgt) * kth) / (float)k;
  if (tid == 0) video[b] = 0.5f * attn + 0.5f * topk;
}

extern "C" void kernel_launch(void* const* d_in, const int* in_sizes, int n_in,
                              void* d_out, int out_size, void* d_ws, size_t ws_size,
                              hipStream_t stream) {
  const float* x    = (const float*)d_in[0];
  const int*   len  = (const int*)  d_in[1];
  const float* W1   = (const float*)d_in[2];
  const float* b1   = (const float*)d_in[3];
  const float* ln_g = (const float*)d_in[4];
  const float* ln_b = (const float*)d_in[5];
  const float* Wa1  = (const float*)d_in[6];
  const float* ba1  = (const float*)d_in[7];
  const float* Wa2  = (const float*)d_in[8];
  const float* ba2  = (const float*)d_in[9];
  const float* Wc   = (const float*)d_in[10];
  const float* bc   = (const float*)d_in[11];

  float* out    = (float*)d_out;
  float* video  = out;
  float* scores = out + Bn;

  char* ws = (char*)d_ws;
  float*          logits = (float*)ws;                                   // 128KB
  unsigned short* wa1bf  = (unsigned short*)(ws + (size_t)Bn * Nn * 4);  // 64KB
  unsigned short* w1bf   = (unsigned short*)(ws + (size_t)Bn * Nn * 4 + (size_t)An * Hn * 2);

  hipLaunchKernelGGL(conv_bf16_kernel, dim3(144), dim3(256), 0, stream, W1, Wa1, w1bf, wa1bf);
  hipLaunchKernelGGL(fused_main, dim3(Bn * Nn / 128), dim3(512), 0, stream,
                     x, b1, ln_g, ln_b, ba1, Wa2, ba2, Wc, bc,
                     w1bf, wa1bf, scores, logits);
  hipLaunchKernelGGL(finalize_kernel, dim3(Bn), dim3(256), 0, stream, len, scores, logits, video);
}